// Round 2
// baseline (548.397 us; speedup 1.0000x reference)
//
#include <hip/hip_runtime.h>
#include <cstdint>
#include <cstddef>

typedef unsigned short u16;
typedef __attribute__((ext_vector_type(8))) unsigned short u16x8;
typedef __attribute__((ext_vector_type(8))) short bf16x8;   // 8 bf16 (4 VGPRs)
typedef __attribute__((ext_vector_type(4))) float f32x4;

#define MFMA_BF16(a, b, c) __builtin_amdgcn_mfma_f32_16x16x32_bf16((a), (b), (c), 0, 0, 0)

__device__ __forceinline__ u16 f2bf(float f) {
  union { float f; uint32_t u; } v; v.f = f;
  uint32_t r = v.u + 0x7fffu + ((v.u >> 16) & 1u);   // RNE
  return (u16)(r >> 16);
}
__device__ __forceinline__ float bf2f(u16 u) {
  union { uint32_t u; float f; } v; v.u = ((uint32_t)u) << 16;
  return v.f;
}
// async global->LDS, 16B per lane; dest must be wave-uniform base + lane*16
__device__ __forceinline__ void gl2lds16(const void* g, void* l) {
  __builtin_amdgcn_global_load_lds((__attribute__((address_space(1))) const void*)g,
                                   (__attribute__((address_space(3))) void*)l, 16, 0, 0);
}

// ---------------------------------------------------------------- prep kernels

__global__ __launch_bounds__(256) void cvt_kernel(const float* __restrict__ in,
                                                  u16* __restrict__ out) {
  int idx = blockIdx.x * 256 + threadIdx.x;
  float4 a = ((const float4*)in)[(size_t)idx * 2];
  float4 b = ((const float4*)in)[(size_t)idx * 2 + 1];
  u16x8 o;
  o[0] = f2bf(a.x); o[1] = f2bf(a.y); o[2] = f2bf(a.z); o[3] = f2bf(a.w);
  o[4] = f2bf(b.x); o[5] = f2bf(b.y); o[6] = f2bf(b.z); o[7] = f2bf(b.w);
  *(u16x8*)(out + (size_t)idx * 8) = o;
}

// out[c][r] = (bf16) in[r][c]   for 2048x2048 f32 -> bf16 (B^T layout)
__global__ __launch_bounds__(256) void trans_kernel(const float* __restrict__ in,
                                                    u16* __restrict__ out) {
  __shared__ float tile[64][65];
  int t = threadIdx.x;
  int r0 = blockIdx.y * 64, c0 = blockIdx.x * 64;
#pragma unroll
  for (int i = 0; i < 16; ++i) {
    int idx = i * 256 + t; int r = idx >> 6, c = idx & 63;
    tile[r][c] = in[(size_t)(r0 + r) * 2048 + c0 + c];
  }
  __syncthreads();
#pragma unroll
  for (int i = 0; i < 16; ++i) {
    int idx = i * 256 + t; int r = idx >> 6, c = idx & 63;
    out[(size_t)(c0 + r) * 2048 + r0 + c] = f2bf(tile[c][r]);
  }
}

// cos/sin table: [B*S][64], double-precision trig (ref is numpy)
__global__ __launch_bounds__(256) void rope_table_kernel(const int* __restrict__ pos,
                                                         float* __restrict__ cosT,
                                                         float* __restrict__ sinT) {
  int idx = blockIdx.x * 256 + threadIdx.x;   // 262144
  int i = idx & 63, t = idx >> 6;
  double ang = (double)pos[t] * exp(-(double)i * (9.210340371976184 / 64.0));
  double s, c;
  sincos(ang, &s, &c);
  cosT[idx] = (float)c;
  sinT[idx] = (float)s;
}

// in-place RoPE on Q (scaled by 1/sqrt(128)) and K, layout [BH][S][128]
__global__ __launch_bounds__(256) void rope_kernel(u16* __restrict__ Q,
                                                   u16* __restrict__ Kk,
                                                   const float* __restrict__ cosT,
                                                   const float* __restrict__ sinT) {
  int idx = blockIdx.x * 256 + threadIdx.x;   // 4194304
  int d = idx & 63, h = (idx >> 6) & 15, tok = idx >> 10;
  int b = tok >> 11, s = tok & 2047;
  size_t base = ((size_t)((b * 16 + h) * 2048 + s)) * 128;
  float c = cosT[(tok << 6) + d], sn = sinT[(tok << 6) + d];
  const float sc = 0.08838834764831845f;   // 1/sqrt(128)
  float q1 = bf2f(Q[base + d]), q2 = bf2f(Q[base + d + 64]);
  Q[base + d]      = f2bf((q1 * c - q2 * sn) * sc);
  Q[base + d + 64] = f2bf((q2 * c + q1 * sn) * sc);
  float k1 = bf2f(Kk[base + d]), k2 = bf2f(Kk[base + d + 64]);
  Kk[base + d]      = f2bf(k1 * c - k2 * sn);
  Kk[base + d + 64] = f2bf(k2 * c + k1 * sn);
}

// V [BH][S][128] -> Vt [BH][128][S]
__global__ __launch_bounds__(256) void vtrans_kernel(const u16* __restrict__ V,
                                                     u16* __restrict__ Vt) {
  __shared__ u16 tile[128][72];
  int t = threadIdx.x;
  int bh = blockIdx.x >> 5, st = blockIdx.x & 31;
  const u16* src = V + ((size_t)bh * 2048 + st * 64) * 128;
#pragma unroll
  for (int i = 0; i < 4; ++i) {
    int idx = i * 256 + t;
    int s = idx >> 4;            // 0..63
    int d0 = (idx & 15) << 3;    // 0..120
    u16x8 v = *(const u16x8*)(src + (size_t)s * 128 + d0);
#pragma unroll
    for (int j = 0; j < 8; ++j) tile[d0 + j][s] = v[j];
  }
  __syncthreads();
  u16* dst = Vt + (size_t)bh * 128 * 2048 + st * 64;
#pragma unroll
  for (int i = 0; i < 4; ++i) {
    int idx = i * 256 + t;
    int d = idx >> 3;            // 0..127
    int s0 = (idx & 7) << 3;     // 0..56
    u16x8 o;
#pragma unroll
    for (int j = 0; j < 8; ++j) o[j] = tile[d][s0 + j];
    *(u16x8*)(dst + (size_t)d * 2048 + s0) = o;
  }
}

// ---------------------------------------------------------------- GEMM (m97 structure)

__global__ __launch_bounds__(256) void gemm1_kernel(
    const u16* __restrict__ A,    // Xb [4096][2048]
    const u16* __restrict__ Bt,   // Wqkv^T [6144][2048]
    const float* __restrict__ bq, const float* __restrict__ bk, const float* __restrict__ bv,
    u16* __restrict__ Qo, u16* __restrict__ Ko, u16* __restrict__ Vo) { // each [32][2048][128]
  __shared__ u16 sA[128 * 32], sB[128 * 32];
  const int K = 2048;
  int t = threadIdx.x, lane = t & 63, wid = t >> 6;
  int bid = (blockIdx.x & 7) * 192 + (blockIdx.x >> 3);   // XCD-chunked (1536 blocks)
  int bm = bid & 31, bn = bid >> 5;
  int m0 = bm << 7, n0 = bn << 7;
  int wr = wid >> 1, wc = wid & 1;
  int fr = lane & 15, fq = lane >> 4;

  const f32x4 vzero = {0.f, 0.f, 0.f, 0.f};
  f32x4 acc[4][4];
#pragma unroll
  for (int m = 0; m < 4; ++m)
#pragma unroll
    for (int n = 0; n < 4; ++n) acc[m][n] = vzero;

  int arow = t >> 2, acol = (t & 3) << 3;
  const u16* ga0 = A + (size_t)(m0 + arow) * K + acol;
  const u16* ga1 = ga0 + (size_t)64 * K;
  const u16* gb0 = Bt + (size_t)(n0 + arow) * K + acol;
  const u16* gb1 = gb0 + (size_t)64 * K;
  u16* lA0 = sA + t * 8; u16* lA1 = sA + 2048 + t * 8;
  u16* lB0 = sB + t * 8; u16* lB1 = sB + 2048 + t * 8;

  for (int k0 = 0; k0 < K; k0 += 32) {
    gl2lds16(ga0 + k0, lA0);
    gl2lds16(ga1 + k0, lA1);
    gl2lds16(gb0 + k0, lB0);
    gl2lds16(gb1 + k0, lB1);
    __syncthreads();
    bf16x8 af[4], bfv[4];
#pragma unroll
    for (int m = 0; m < 4; ++m)
      af[m] = *(const bf16x8*)(sA + ((wr * 64 + m * 16 + fr) * 32 + fq * 8));
#pragma unroll
    for (int n = 0; n < 4; ++n)
      bfv[n] = *(const bf16x8*)(sB + ((wc * 64 + n * 16 + fr) * 32 + fq * 8));
#pragma unroll
    for (int m = 0; m < 4; ++m)
#pragma unroll
      for (int n = 0; n < 4; ++n)
        acc[m][n] = MFMA_BF16(af[m], bfv[n], acc[m][n]);
    __syncthreads();
  }
#pragma unroll
  for (int n = 0; n < 4; ++n) {
    int col = n0 + wc * 64 + n * 16 + fr;
    int which = col >> 11;
    int cin = col & 2047;
    const float* bp = (which == 0) ? bq : (which == 1) ? bk : bv;
    u16* dst = (which == 0) ? Qo : (which == 1) ? Ko : Vo;
    float bias = bp[cin];
    int h = cin >> 7, d = cin & 127;
#pragma unroll
    for (int m = 0; m < 4; ++m) {
      int row = m0 + wr * 64 + m * 16 + fq * 4;
#pragma unroll
      for (int r = 0; r < 4; ++r) {
        int tok = row + r;
        int b = tok >> 11, s = tok & 2047;
        dst[((size_t)((b * 16 + h) * 2048 + s) << 7) + d] = f2bf(acc[m][n][r] + bias);
      }
    }
  }
}

__global__ __launch_bounds__(256) void gemm2_kernel(
    const u16* __restrict__ A,    // AO [4096][2048]
    const u16* __restrict__ Bt,   // Wo^T [2048][2048]
    float* __restrict__ C) {      // out [4096][2048] f32
  __shared__ u16 sA[128 * 32], sB[128 * 32];
  const int K = 2048;
  int t = threadIdx.x, lane = t & 63, wid = t >> 6;
  int bid = (blockIdx.x & 7) * 64 + (blockIdx.x >> 3);    // XCD-chunked (512 blocks)
  int bm = bid & 31, bn = bid >> 5;
  int m0 = bm << 7, n0 = bn << 7;
  int wr = wid >> 1, wc = wid & 1;
  int fr = lane & 15, fq = lane >> 4;

  const f32x4 vzero = {0.f, 0.f, 0.f, 0.f};
  f32x4 acc[4][4];
#pragma unroll
  for (int m = 0; m < 4; ++m)
#pragma unroll
    for (int n = 0; n < 4; ++n) acc[m][n] = vzero;

  int arow = t >> 2, acol = (t & 3) << 3;
  const u16* ga0 = A + (size_t)(m0 + arow) * K + acol;
  const u16* ga1 = ga0 + (size_t)64 * K;
  const u16* gb0 = Bt + (size_t)(n0 + arow) * K + acol;
  const u16* gb1 = gb0 + (size_t)64 * K;
  u16* lA0 = sA + t * 8; u16* lA1 = sA + 2048 + t * 8;
  u16* lB0 = sB + t * 8; u16* lB1 = sB + 2048 + t * 8;

  for (int k0 = 0; k0 < K; k0 += 32) {
    gl2lds16(ga0 + k0, lA0);
    gl2lds16(ga1 + k0, lA1);
    gl2lds16(gb0 + k0, lB0);
    gl2lds16(gb1 + k0, lB1);
    __syncthreads();
    bf16x8 af[4], bfv[4];
#pragma unroll
    for (int m = 0; m < 4; ++m)
      af[m] = *(const bf16x8*)(sA + ((wr * 64 + m * 16 + fr) * 32 + fq * 8));
#pragma unroll
    for (int n = 0; n < 4; ++n)
      bfv[n] = *(const bf16x8*)(sB + ((wc * 64 + n * 16 + fr) * 32 + fq * 8));
#pragma unroll
    for (int m = 0; m < 4; ++m)
#pragma unroll
      for (int n = 0; n < 4; ++n)
        acc[m][n] = MFMA_BF16(af[m], bfv[n], acc[m][n]);
    __syncthreads();
  }
#pragma unroll
  for (int n = 0; n < 4; ++n) {
    int col = n0 + wc * 64 + n * 16 + fr;
#pragma unroll
    for (int m = 0; m < 4; ++m) {
      int row = m0 + wr * 64 + m * 16 + fq * 4;
#pragma unroll
      for (int r = 0; r < 4; ++r)
        C[(size_t)(row + r) * 2048 + col] = acc[m][n][r];
    }
  }
}

// ---------------------------------------------------------------- flash attention
// block = (bh, q-tile 128). 4 waves x 32 q rows (2 row-frags each). KV tile 64.
// K tile LDS [64][128] bf16, V^T tile [128][64], double-buffered, XOR-swizzled
// byte ^= ((row&7)<<4) via pre-swizzled global src (linear LDS dest).
__global__ __launch_bounds__(256) void attn_kernel(
    const u16* __restrict__ Q_,   // [32][2048][128] rope'd, pre-scaled
    const u16* __restrict__ K_,   // [32][2048][128] rope'd
    const u16* __restrict__ Vt_,  // [32][128][2048]
    u16* __restrict__ AO) {       // [4096][2048]
  __shared__ u16 sK[2][64 * 128];
  __shared__ u16 sV[2][128 * 64];
  __shared__ u16 sP[4][32 * 64];
  int t = threadIdx.x, lane = t & 63, wid = t >> 6;
  int fr = lane & 15, fq = lane >> 4;
  int bid = (blockIdx.x & 7) * 64 + (blockIdx.x >> 3);    // XCD-chunked (512 blocks)
  int qt = bid & 15, bh = bid >> 4;
  int q0 = qt << 7;
  const u16* Qb = Q_ + (size_t)bh * 2048 * 128;
  const char* Kc = (const char*)(K_ + (size_t)bh * 2048 * 128);
  const char* Vc = (const char*)(Vt_ + (size_t)bh * 128 * 2048);

  // Q fragments: wave rows q0 + wid*32 + m*16 + fr
  bf16x8 qf[2][4];
#pragma unroll
  for (int m = 0; m < 2; ++m) {
    const u16* qp = Qb + (size_t)(q0 + wid * 32 + m * 16 + fr) * 128 + fq * 8;
#pragma unroll
    for (int kk = 0; kk < 4; ++kk) qf[m][kk] = *(const bf16x8*)(qp + kk * 32);
  }

  // staging offsets (pre-swizzled global source, linear LDS dest)
  int kgoff[4], kldst[4], vgoff[4], vldst[4];
#pragma unroll
  for (int i = 0; i < 4; ++i) {
    int kr = i * 16 + (t >> 4);
    kgoff[i] = kr * 256 + (((t & 15) << 4) ^ ((kr & 7) << 4));
    kldst[i] = i * 4096 + t * 16;
    int vr = i * 32 + (t >> 3);
    vgoff[i] = vr * 4096 + (((t & 7) << 4) ^ ((vr & 7) << 4));
    vldst[i] = i * 4096 + t * 16;
  }

#define STAGE(tt, bb)                                                          \
  {                                                                            \
    size_t ko = (size_t)(tt) * 64 * 256;                                       \
    size_t vo = (size_t)(tt) * 128;                                            \
    _Pragma("unroll")                                                          \
    for (int i = 0; i < 4; ++i)                                                \
      gl2lds16(Kc + ko + kgoff[i], (char*)sK[bb] + kldst[i]);                  \
    _Pragma("unroll")                                                          \
    for (int i = 0; i < 4; ++i)                                                \
      gl2lds16(Vc + vo + vgoff[i], (char*)sV[bb] + vldst[i]);                  \
  }

  float mrun[2][4], lrun[2][4];
#pragma unroll
  for (int m = 0; m < 2; ++m)
#pragma unroll
    for (int r = 0; r < 4; ++r) { mrun[m][r] = -1e30f; lrun[m][r] = 0.f; }
  const f32x4 vzero = {0.f, 0.f, 0.f, 0.f};
  f32x4 oacc[2][8];
#pragma unroll
  for (int m = 0; m < 2; ++m)
#pragma unroll
    for (int fd = 0; fd < 8; ++fd) oacc[m][fd] = vzero;

  char* sPw = (char*)sP[wid];

  STAGE(0, 0);
  __syncthreads();

  for (int tile = 0; tile < 32; ++tile) {
    int cur = tile & 1;
    if (tile < 31) STAGE(tile + 1, cur ^ 1);   // in flight during compute
    const char* Kb_ = (const char*)sK[cur];
    const char* Vb_ = (const char*)sV[cur];

    // S = Q @ K^T
    f32x4 sacc[2][4];
#pragma unroll
    for (int m = 0; m < 2; ++m)
#pragma unroll
      for (int n = 0; n < 4; ++n) sacc[m][n] = vzero;
    __builtin_amdgcn_s_setprio(1);
#pragma unroll
    for (int n = 0; n < 4; ++n) {
      int krow = n * 16 + fr;
      int swz = (krow & 7) << 4;
      const char* kbase = Kb_ + krow * 256;
#pragma unroll
      for (int kk = 0; kk < 4; ++kk) {
        bf16x8 kf = *(const bf16x8*)(kbase + ((kk * 64 + fq * 16) ^ swz));
        sacc[0][n] = MFMA_BF16(qf[0][kk], kf, sacc[0][n]);
        sacc[1][n] = MFMA_BF16(qf[1][kk], kf, sacc[1][n]);
      }
    }
    __builtin_amdgcn_s_setprio(0);

    // online softmax with defer-max (THR=8)
    float pmax[2][4];
#pragma unroll
    for (int m = 0; m < 2; ++m)
#pragma unroll
      for (int r = 0; r < 4; ++r) {
        float v = fmaxf(fmaxf(sacc[m][0][r], sacc[m][1][r]),
                        fmaxf(sacc[m][2][r], sacc[m][3][r]));
        v = fmaxf(v, __shfl_xor(v, 1));
        v = fmaxf(v, __shfl_xor(v, 2));
        v = fmaxf(v, __shfl_xor(v, 4));
        v = fmaxf(v, __shfl_xor(v, 8));
        pmax[m][r] = v;
      }
    int ok = 1;
#pragma unroll
    for (int m = 0; m < 2; ++m)
#pragma unroll
      for (int r = 0; r < 4; ++r)
        ok &= (pmax[m][r] <= mrun[m][r] + 8.f) ? 1 : 0;
    if (!__all(ok)) {
#pragma unroll
      for (int m = 0; m < 2; ++m)
#pragma unroll
        for (int r = 0; r < 4; ++r) {
          float mn = fmaxf(mrun[m][r], pmax[m][r]);
          float scl = __expf(mrun[m][r] - mn);
          mrun[m][r] = mn;
          lrun[m][r] *= scl;
#pragma unroll
          for (int fd = 0; fd < 8; ++fd) oacc[m][fd][r] *= scl;
        }
    }
    float rs[2][4] = {{0.f, 0.f, 0.f, 0.f}, {0.f, 0.f, 0.f, 0.f}};
#pragma unroll
    for (int m = 0; m < 2; ++m)
#pragma unroll
      for (int n = 0; n < 4; ++n)
#pragma unroll
        for (int r = 0; r < 4; ++r) {
          float p = __expf(sacc[m][n][r] - mrun[m][r]);
          rs[m][r] += p;
          int q = m * 16 + fq * 4 + r;
          *(u16*)(sPw + q * 128 + ((((n * 16 + fr) << 1)) ^ ((q & 7) << 4))) = f2bf(p);
        }
#pragma unroll
    for (int m = 0; m < 2; ++m)
#pragma unroll
      for (int r = 0; r < 4; ++r) {
        float s = rs[m][r];
        s += __shfl_xor(s, 1);
        s += __shfl_xor(s, 2);
        s += __shfl_xor(s, 4);
        s += __shfl_xor(s, 8);
        lrun[m][r] += s;
      }

    // O += P @ V
    bf16x8 pf[2][2];
#pragma unroll
    for (int m = 0; m < 2; ++m)
#pragma unroll
      for (int kk = 0; kk < 2; ++kk)
        pf[m][kk] = *(const bf16x8*)(sPw + (m * 16 + fr) * 128 +
                                     ((kk * 64 + fq * 16) ^ ((fr & 7) << 4)));
    __builtin_amdgcn_s_setprio(1);
#pragma unroll
    for (int fd = 0; fd < 8; ++fd) {
      int vrow = fd * 16 + fr;
      int vswz = (vrow & 7) << 4;
      const char* vbase = Vb_ + vrow * 128;
#pragma unroll
      for (int kk = 0; kk < 2; ++kk) {
        bf16x8 vf = *(const bf16x8*)(vbase + ((kk * 64 + fq * 16) ^ vswz));
        oacc[0][fd] = MFMA_BF16(pf[0][kk], vf, oacc[0][fd]);
        oacc[1][fd] = MFMA_BF16(pf[1][kk], vf, oacc[1][fd]);
      }
    }
    __builtin_amdgcn_s_setprio(0);
    __syncthreads();   // drains vmcnt (next buffer ready) + guards cur reuse
  }
#undef STAGE

  int h = bh & 15, b = bh >> 4;
#pragma unroll
  for (int m = 0; m < 2; ++m)
#pragma unroll
    for (int r = 0; r < 4; ++r) {
      float inv = 1.f / lrun[m][r];
      int tok = b * 2048 + q0 + wid * 32 + m * 16 + fq * 4 + r;
#pragma unroll
      for (int fd = 0; fd < 8; ++fd) {
        int col = h * 128 + fd * 16 + fr;
        AO[(size_t)tok * 2048 + col] = f2bf(oacc[m][fd][r] * inv);
      }
    }
}

// ---------------------------------------------------------------- launcher

extern "C" void kernel_launch(void* const* d_in, const int* in_sizes, int n_in,
                              void* d_out, int out_size, void* d_ws, size_t ws_size,
                              hipStream_t stream) {
  (void)in_sizes; (void)n_in; (void)out_size; (void)ws_size;
  const int*   positions = (const int*)d_in[0];
  const float* hidden    = (const float*)d_in[1];
  const float* Wq = (const float*)d_in[2];
  const float* bq = (const float*)d_in[3];
  const float* Wk = (const float*)d_in[4];
  const float* bk = (const float*)d_in[5];
  const float* Wv = (const float*)d_in[6];
  const float* bv = (const float*)d_in[7];
  const float* Wo = (const float*)d_in[8];
  float* out = (float*)d_out;

  char* ws = (char*)d_ws;
  u16*   Xb   = (u16*)(ws);                     // 16 MB  [4096][2048]
  u16*   Wt   = (u16*)(ws + 16777216);          // 24 MB  [6144][2048]
  u16*   Wot  = (u16*)(ws + 41943040);          //  8 MB  [2048][2048]
  u16*   Qb   = (u16*)(ws + 50331648);          // 16 MB  [32][2048][128]
  u16*   Kb   = (u16*)(ws + 67108864);          // 16 MB
  u16*   Vb   = (u16*)(ws + 83886080);          // 16 MB
  u16*   Vtb  = (u16*)(ws + 100663296);         // 16 MB  [32][128][2048]
  u16*   AO   = (u16*)(ws + 117440512);         // 16 MB  [4096][2048]
  float* cosT = (float*)(ws + 134217728);       //  1 MB
  float* sinT = (float*)(ws + 135266304);       //  1 MB  (end ~130 MB)

  cvt_kernel<<<4096, 256, 0, stream>>>(hidden, Xb);
  trans_kernel<<<dim3(32, 32), 256, 0, stream>>>(Wq, Wt);
  trans_kernel<<<dim3(32, 32), 256, 0, stream>>>(Wk, Wt + (size_t)2048 * 2048);
  trans_kernel<<<dim3(32, 32), 256, 0, stream>>>(Wv, Wt + (size_t)2 * 2048 * 2048);
  trans_kernel<<<dim3(32, 32), 256, 0, stream>>>(Wo, Wot);
  rope_table_kernel<<<1024, 256, 0, stream>>>(positions, cosT, sinT);
  gemm1_kernel<<<1536, 256, 0, stream>>>(Xb, Wt, bq, bk, bv, Qb, Kb, Vb);
  rope_kernel<<<16384, 256, 0, stream>>>(Qb, Kb, cosT, sinT);
  vtrans_kernel<<<1024, 256, 0, stream>>>(Vb, Vtb);
  attn_kernel<<<512, 256, 0, stream>>>(Qb, Kb, Vtb, AO);
  gemm2_kernel<<<512, 256, 0, stream>>>(AO, Wot, out);
}

// Round 3
// 473.729 us; speedup vs baseline: 1.1576x; 1.1576x over previous
//
#include <hip/hip_runtime.h>
#include <cstdint>
#include <cstddef>

typedef unsigned short u16;
typedef __attribute__((ext_vector_type(8))) unsigned short u16x8;
typedef __attribute__((ext_vector_type(8))) short bf16x8;   // 8 bf16 (4 VGPRs)
typedef __attribute__((ext_vector_type(4))) float f32x4;

#define MFMA_BF16(a, b, c) __builtin_amdgcn_mfma_f32_16x16x32_bf16((a), (b), (c), 0, 0, 0)

__device__ __forceinline__ u16 f2bf(float f) {
  union { float f; uint32_t u; } v; v.f = f;
  uint32_t r = v.u + 0x7fffu + ((v.u >> 16) & 1u);   // RNE
  return (u16)(r >> 16);
}
__device__ __forceinline__ float bf2f(u16 u) {
  union { uint32_t u; float f; } v; v.u = ((uint32_t)u) << 16;
  return v.f;
}
// async global->LDS, 16B per lane; dest must be wave-uniform base + lane*16
__device__ __forceinline__ void gl2lds16(const void* g, void* l) {
  __builtin_amdgcn_global_load_lds((__attribute__((address_space(1))) const void*)g,
                                   (__attribute__((address_space(3))) void*)l, 16, 0, 0);
}

// ---------------------------------------------------------------- prep kernels

__global__ __launch_bounds__(256) void cvt_kernel(const float* __restrict__ in,
                                                  u16* __restrict__ out) {
  int idx = blockIdx.x * 256 + threadIdx.x;
  float4 a = ((const float4*)in)[(size_t)idx * 2];
  float4 b = ((const float4*)in)[(size_t)idx * 2 + 1];
  u16x8 o;
  o[0] = f2bf(a.x); o[1] = f2bf(a.y); o[2] = f2bf(a.z); o[3] = f2bf(a.w);
  o[4] = f2bf(b.x); o[5] = f2bf(b.y); o[6] = f2bf(b.z); o[7] = f2bf(b.w);
  *(u16x8*)(out + (size_t)idx * 8) = o;
}

// out[c][r] = (bf16) in[r][c]   for 2048x2048 f32 -> bf16 (B^T layout)
__global__ __launch_bounds__(256) void trans_kernel(const float* __restrict__ in,
                                                    u16* __restrict__ out) {
  __shared__ float tile[64][65];
  int t = threadIdx.x;
  int r0 = blockIdx.y * 64, c0 = blockIdx.x * 64;
#pragma unroll
  for (int i = 0; i < 16; ++i) {
    int idx = i * 256 + t; int r = idx >> 6, c = idx & 63;
    tile[r][c] = in[(size_t)(r0 + r) * 2048 + c0 + c];
  }
  __syncthreads();
#pragma unroll
  for (int i = 0; i < 16; ++i) {
    int idx = i * 256 + t; int r = idx >> 6, c = idx & 63;
    out[(size_t)(c0 + r) * 2048 + r0 + c] = f2bf(tile[c][r]);
  }
}

// cos/sin table: [B*S][64], double-precision trig (ref is numpy)
__global__ __launch_bounds__(256) void rope_table_kernel(const int* __restrict__ pos,
                                                         float* __restrict__ cosT,
                                                         float* __restrict__ sinT) {
  int idx = blockIdx.x * 256 + threadIdx.x;   // 262144
  int i = idx & 63, t = idx >> 6;
  double ang = (double)pos[t] * exp(-(double)i * (9.210340371976184 / 64.0));
  double s, c;
  sincos(ang, &s, &c);
  cosT[idx] = (float)c;
  sinT[idx] = (float)s;
}

// in-place RoPE on Q (scaled by 1/sqrt(128)) and K, layout [BH][S][128]
__global__ __launch_bounds__(256) void rope_kernel(u16* __restrict__ Q,
                                                   u16* __restrict__ Kk,
                                                   const float* __restrict__ cosT,
                                                   const float* __restrict__ sinT) {
  int idx = blockIdx.x * 256 + threadIdx.x;   // 4194304
  int d = idx & 63, h = (idx >> 6) & 15, tok = idx >> 10;
  int b = tok >> 11, s = tok & 2047;
  size_t base = ((size_t)((b * 16 + h) * 2048 + s)) * 128;
  float c = cosT[(tok << 6) + d], sn = sinT[(tok << 6) + d];
  const float sc = 0.08838834764831845f;   // 1/sqrt(128)
  float q1 = bf2f(Q[base + d]), q2 = bf2f(Q[base + d + 64]);
  Q[base + d]      = f2bf((q1 * c - q2 * sn) * sc);
  Q[base + d + 64] = f2bf((q2 * c + q1 * sn) * sc);
  float k1 = bf2f(Kk[base + d]), k2 = bf2f(Kk[base + d + 64]);
  Kk[base + d]      = f2bf(k1 * c - k2 * sn);
  Kk[base + d + 64] = f2bf(k2 * c + k1 * sn);
}

// V [BH][S][128] -> Vt [BH][128][S]
__global__ __launch_bounds__(256) void vtrans_kernel(const u16* __restrict__ V,
                                                     u16* __restrict__ Vt) {
  __shared__ u16 tile[128][72];
  int t = threadIdx.x;
  int bh = blockIdx.x >> 5, st = blockIdx.x & 31;
  const u16* src = V + ((size_t)bh * 2048 + st * 64) * 128;
#pragma unroll
  for (int i = 0; i < 4; ++i) {
    int idx = i * 256 + t;
    int s = idx >> 4;            // 0..63
    int d0 = (idx & 15) << 3;    // 0..120
    u16x8 v = *(const u16x8*)(src + (size_t)s * 128 + d0);
#pragma unroll
    for (int j = 0; j < 8; ++j) tile[d0 + j][s] = v[j];
  }
  __syncthreads();
  u16* dst = Vt + (size_t)bh * 128 * 2048 + st * 64;
#pragma unroll
  for (int i = 0; i < 4; ++i) {
    int idx = i * 256 + t;
    int d = idx >> 3;            // 0..127
    int s0 = (idx & 7) << 3;     // 0..56
    u16x8 o;
#pragma unroll
    for (int j = 0; j < 8; ++j) o[j] = tile[d][s0 + j];
    *(u16x8*)(dst + (size_t)d * 2048 + s0) = o;
  }
}

// ---------------------------------------------------------------- GEMM (m97 structure)

__global__ __launch_bounds__(256) void gemm1_kernel(
    const u16* __restrict__ A,    // Xb [4096][2048]
    const u16* __restrict__ Bt,   // Wqkv^T [6144][2048]
    const float* __restrict__ bq, const float* __restrict__ bk, const float* __restrict__ bv,
    u16* __restrict__ Qo, u16* __restrict__ Ko, u16* __restrict__ Vo) { // each [32][2048][128]
  __shared__ u16 sA[128 * 32], sB[128 * 32];
  const int K = 2048;
  int t = threadIdx.x, lane = t & 63, wid = t >> 6;
  int bm = blockIdx.x & 31, bn = blockIdx.x >> 5;
  int m0 = bm << 7, n0 = bn << 7;
  int wr = wid >> 1, wc = wid & 1;
  int fr = lane & 15, fq = lane >> 4;

  const f32x4 vzero = {0.f, 0.f, 0.f, 0.f};
  f32x4 acc[4][4];
#pragma unroll
  for (int m = 0; m < 4; ++m)
#pragma unroll
    for (int n = 0; n < 4; ++n) acc[m][n] = vzero;

  int arow = t >> 2, acol = (t & 3) << 3;
  const u16* ga0 = A + (size_t)(m0 + arow) * K + acol;
  const u16* ga1 = ga0 + (size_t)64 * K;
  const u16* gb0 = Bt + (size_t)(n0 + arow) * K + acol;
  const u16* gb1 = gb0 + (size_t)64 * K;
  u16* lA0 = sA + t * 8; u16* lA1 = sA + 2048 + t * 8;
  u16* lB0 = sB + t * 8; u16* lB1 = sB + 2048 + t * 8;

  for (int k0 = 0; k0 < K; k0 += 32) {
    gl2lds16(ga0 + k0, lA0);
    gl2lds16(ga1 + k0, lA1);
    gl2lds16(gb0 + k0, lB0);
    gl2lds16(gb1 + k0, lB1);
    __syncthreads();
    bf16x8 af[4], bfv[4];
#pragma unroll
    for (int m = 0; m < 4; ++m)
      af[m] = *(const bf16x8*)(sA + ((wr * 64 + m * 16 + fr) * 32 + fq * 8));
#pragma unroll
    for (int n = 0; n < 4; ++n)
      bfv[n] = *(const bf16x8*)(sB + ((wc * 64 + n * 16 + fr) * 32 + fq * 8));
#pragma unroll
    for (int m = 0; m < 4; ++m)
#pragma unroll
      for (int n = 0; n < 4; ++n)
        acc[m][n] = MFMA_BF16(af[m], bfv[n], acc[m][n]);
    __syncthreads();
  }
#pragma unroll
  for (int n = 0; n < 4; ++n) {
    int col = n0 + wc * 64 + n * 16 + fr;
    int which = col >> 11;
    int cin = col & 2047;
    const float* bp = (which == 0) ? bq : (which == 1) ? bk : bv;
    u16* dst = (which == 0) ? Qo : (which == 1) ? Ko : Vo;
    float bias = bp[cin];
    int h = cin >> 7, d = cin & 127;
#pragma unroll
    for (int m = 0; m < 4; ++m) {
      int row = m0 + wr * 64 + m * 16 + fq * 4;
#pragma unroll
      for (int r = 0; r < 4; ++r) {
        int tok = row + r;
        int b = tok >> 11, s = tok & 2047;
        dst[((size_t)((b * 16 + h) * 2048 + s) << 7) + d] = f2bf(acc[m][n][r] + bias);
      }
    }
  }
}

__global__ __launch_bounds__(256) void gemm2_kernel(
    const u16* __restrict__ A,    // AO [4096][2048]
    const u16* __restrict__ Bt,   // Wo^T [2048][2048]
    float* __restrict__ C) {      // out [4096][2048] f32
  __shared__ u16 sA[128 * 32], sB[128 * 32];
  const int K = 2048;
  int t = threadIdx.x, lane = t & 63, wid = t >> 6;
  int bm = blockIdx.x & 31, bn = blockIdx.x >> 5;
  int m0 = bm << 7, n0 = bn << 7;
  int wr = wid >> 1, wc = wid & 1;
  int fr = lane & 15, fq = lane >> 4;

  const f32x4 vzero = {0.f, 0.f, 0.f, 0.f};
  f32x4 acc[4][4];
#pragma unroll
  for (int m = 0; m < 4; ++m)
#pragma unroll
    for (int n = 0; n < 4; ++n) acc[m][n] = vzero;

  int arow = t >> 2, acol = (t & 3) << 3;
  const u16* ga0 = A + (size_t)(m0 + arow) * K + acol;
  const u16* ga1 = ga0 + (size_t)64 * K;
  const u16* gb0 = Bt + (size_t)(n0 + arow) * K + acol;
  const u16* gb1 = gb0 + (size_t)64 * K;
  u16* lA0 = sA + t * 8; u16* lA1 = sA + 2048 + t * 8;
  u16* lB0 = sB + t * 8; u16* lB1 = sB + 2048 + t * 8;

  for (int k0 = 0; k0 < K; k0 += 32) {
    gl2lds16(ga0 + k0, lA0);
    gl2lds16(ga1 + k0, lA1);
    gl2lds16(gb0 + k0, lB0);
    gl2lds16(gb1 + k0, lB1);
    __syncthreads();
    bf16x8 af[4], bfv[4];
#pragma unroll
    for (int m = 0; m < 4; ++m)
      af[m] = *(const bf16x8*)(sA + ((wr * 64 + m * 16 + fr) * 32 + fq * 8));
#pragma unroll
    for (int n = 0; n < 4; ++n)
      bfv[n] = *(const bf16x8*)(sB + ((wc * 64 + n * 16 + fr) * 32 + fq * 8));
#pragma unroll
    for (int m = 0; m < 4; ++m)
#pragma unroll
      for (int n = 0; n < 4; ++n)
        acc[m][n] = MFMA_BF16(af[m], bfv[n], acc[m][n]);
    __syncthreads();
  }
#pragma unroll
  for (int n = 0; n < 4; ++n) {
    int col = n0 + wc * 64 + n * 16 + fr;
#pragma unroll
    for (int m = 0; m < 4; ++m) {
      int row = m0 + wr * 64 + m * 16 + fq * 4;
#pragma unroll
      for (int r = 0; r < 4; ++r)
        C[(size_t)(row + r) * 2048 + col] = acc[m][n][r];
    }
  }
}

// ---------------------------------------------------------------- flash attention
// block = (bh, q-tile 256). 8 waves x 32 q rows (2 row-frags each). KV tile 64.
// 256 blocks = exactly 1/CU, 8 waves/CU = 2/SIMD. LDS 96KB.
// K tile LDS [64][128] bf16, V^T tile [128][64], double-buffered, XOR-swizzled
// byte ^= ((row&7)<<4) via pre-swizzled global src (linear LDS dest).
__global__ __launch_bounds__(512) void attn_kernel(
    const u16* __restrict__ Q_,   // [32][2048][128] rope'd, pre-scaled
    const u16* __restrict__ K_,   // [32][2048][128] rope'd
    const u16* __restrict__ Vt_,  // [32][128][2048]
    u16* __restrict__ AO) {       // [4096][2048]
  __shared__ u16 sK[2][64 * 128];
  __shared__ u16 sV[2][128 * 64];
  __shared__ u16 sP[8][32 * 64];
  int t = threadIdx.x, lane = t & 63, wid = t >> 6;
  int fr = lane & 15, fq = lane >> 4;
  int qt = blockIdx.x & 7, bh = blockIdx.x >> 3;
  int q0 = qt << 8;
  const u16* Qb = Q_ + (size_t)bh * 2048 * 128;
  const char* Kc = (const char*)(K_ + (size_t)bh * 2048 * 128);
  const char* Vc = (const char*)(Vt_ + (size_t)bh * 128 * 2048);

  // Q fragments: wave rows q0 + wid*32 + m*16 + fr
  bf16x8 qf[2][4];
#pragma unroll
  for (int m = 0; m < 2; ++m) {
    const u16* qp = Qb + (size_t)(q0 + wid * 32 + m * 16 + fr) * 128 + fq * 8;
#pragma unroll
    for (int kk = 0; kk < 4; ++kk) qf[m][kk] = *(const bf16x8*)(qp + kk * 32);
  }

  // staging offsets (pre-swizzled global source, linear LDS dest); 512 threads
  int kgoff[2], kldst[2], vgoff[2], vldst[2];
#pragma unroll
  for (int i = 0; i < 2; ++i) {
    int kr = i * 32 + (t >> 4);          // K rows 0..63, 16 lanes/row (256B)
    kgoff[i] = kr * 256 + (((t & 15) << 4) ^ ((kr & 7) << 4));
    kldst[i] = i * 8192 + t * 16;
    int vr = i * 64 + (t >> 3);          // V rows 0..127, 8 lanes/row (128B)
    vgoff[i] = vr * 4096 + (((t & 7) << 4) ^ ((vr & 7) << 4));
    vldst[i] = i * 8192 + t * 16;
  }

#define STAGE(tt, bb)                                                          \
  {                                                                            \
    size_t ko = (size_t)(tt) * 16384;                                          \
    size_t vo = (size_t)(tt) * 128;                                            \
    _Pragma("unroll")                                                          \
    for (int i = 0; i < 2; ++i)                                                \
      gl2lds16(Kc + ko + kgoff[i], (char*)sK[bb] + kldst[i]);                  \
    _Pragma("unroll")                                                          \
    for (int i = 0; i < 2; ++i)                                                \
      gl2lds16(Vc + vo + vgoff[i], (char*)sV[bb] + vldst[i]);                  \
  }

  float mrun[2][4], lrun[2][4];
#pragma unroll
  for (int m = 0; m < 2; ++m)
#pragma unroll
    for (int r = 0; r < 4; ++r) { mrun[m][r] = -1e30f; lrun[m][r] = 0.f; }
  const f32x4 vzero = {0.f, 0.f, 0.f, 0.f};
  f32x4 oacc[2][8];
#pragma unroll
  for (int m = 0; m < 2; ++m)
#pragma unroll
    for (int fd = 0; fd < 8; ++fd) oacc[m][fd] = vzero;

  char* sPw = (char*)sP[wid];

  STAGE(0, 0);
  __syncthreads();

  for (int tile = 0; tile < 32; ++tile) {
    int cur = tile & 1;
    if (tile < 31) STAGE(tile + 1, cur ^ 1);   // in flight during compute
    const char* Kb_ = (const char*)sK[cur];
    const char* Vb_ = (const char*)sV[cur];

    // S = Q @ K^T
    f32x4 sacc[2][4];
#pragma unroll
    for (int m = 0; m < 2; ++m)
#pragma unroll
      for (int n = 0; n < 4; ++n) sacc[m][n] = vzero;
    __builtin_amdgcn_s_setprio(1);
#pragma unroll
    for (int n = 0; n < 4; ++n) {
      int krow = n * 16 + fr;
      int swz = (krow & 7) << 4;
      const char* kbase = Kb_ + krow * 256;
#pragma unroll
      for (int kk = 0; kk < 4; ++kk) {
        bf16x8 kf = *(const bf16x8*)(kbase + ((kk * 64 + fq * 16) ^ swz));
        sacc[0][n] = MFMA_BF16(qf[0][kk], kf, sacc[0][n]);
        sacc[1][n] = MFMA_BF16(qf[1][kk], kf, sacc[1][n]);
      }
    }
    __builtin_amdgcn_s_setprio(0);

    // online softmax with defer-max (THR=8)
    float pmax[2][4];
#pragma unroll
    for (int m = 0; m < 2; ++m)
#pragma unroll
      for (int r = 0; r < 4; ++r) {
        float v = fmaxf(fmaxf(sacc[m][0][r], sacc[m][1][r]),
                        fmaxf(sacc[m][2][r], sacc[m][3][r]));
        v = fmaxf(v, __shfl_xor(v, 1));
        v = fmaxf(v, __shfl_xor(v, 2));
        v = fmaxf(v, __shfl_xor(v, 4));
        v = fmaxf(v, __shfl_xor(v, 8));
        pmax[m][r] = v;
      }
    int ok = 1;
#pragma unroll
    for (int m = 0; m < 2; ++m)
#pragma unroll
      for (int r = 0; r < 4; ++r)
        ok &= (pmax[m][r] <= mrun[m][r] + 8.f) ? 1 : 0;
    if (!__all(ok)) {
#pragma unroll
      for (int m = 0; m < 2; ++m)
#pragma unroll
        for (int r = 0; r < 4; ++r) {
          float mn = fmaxf(mrun[m][r], pmax[m][r]);
          float scl = __expf(mrun[m][r] - mn);
          mrun[m][r] = mn;
          lrun[m][r] *= scl;
#pragma unroll
          for (int fd = 0; fd < 8; ++fd) oacc[m][fd][r] *= scl;
        }
    }
    float rs[2][4] = {{0.f, 0.f, 0.f, 0.f}, {0.f, 0.f, 0.f, 0.f}};
#pragma unroll
    for (int m = 0; m < 2; ++m)
#pragma unroll
      for (int n = 0; n < 4; ++n)
#pragma unroll
        for (int r = 0; r < 4; ++r) {
          float p = __expf(sacc[m][n][r] - mrun[m][r]);
          rs[m][r] += p;
          int q = m * 16 + fq * 4 + r;
          *(u16*)(sPw + q * 128 + ((((n * 16 + fr) << 1)) ^ ((q & 7) << 4))) = f2bf(p);
        }
#pragma unroll
    for (int m = 0; m < 2; ++m)
#pragma unroll
      for (int r = 0; r < 4; ++r) {
        float s = rs[m][r];
        s += __shfl_xor(s, 1);
        s += __shfl_xor(s, 2);
        s += __shfl_xor(s, 4);
        s += __shfl_xor(s, 8);
        lrun[m][r] += s;
      }

    // O += P @ V
    bf16x8 pf[2][2];
#pragma unroll
    for (int m = 0; m < 2; ++m)
#pragma unroll
      for (int kk = 0; kk < 2; ++kk)
        pf[m][kk] = *(const bf16x8*)(sPw + (m * 16 + fr) * 128 +
                                     ((kk * 64 + fq * 16) ^ ((fr & 7) << 4)));
    __builtin_amdgcn_s_setprio(1);
#pragma unroll
    for (int fd = 0; fd < 8; ++fd) {
      int vrow = fd * 16 + fr;
      int vswz = (vrow & 7) << 4;
      const char* vbase = Vb_ + vrow * 128;
#pragma unroll
      for (int kk = 0; kk < 2; ++kk) {
        bf16x8 vf = *(const bf16x8*)(vbase + ((kk * 64 + fq * 16) ^ vswz));
        oacc[0][fd] = MFMA_BF16(pf[0][kk], vf, oacc[0][fd]);
        oacc[1][fd] = MFMA_BF16(pf[1][kk], vf, oacc[1][fd]);
      }
    }
    __builtin_amdgcn_s_setprio(0);
    __syncthreads();   // drains vmcnt (next buffer ready) + guards cur reuse
  }
#undef STAGE

  int h = bh & 15, b = bh >> 4;
#pragma unroll
  for (int m = 0; m < 2; ++m)
#pragma unroll
    for (int r = 0; r < 4; ++r) {
      float inv = 1.f / lrun[m][r];
      int tok = b * 2048 + q0 + wid * 32 + m * 16 + fq * 4 + r;
#pragma unroll
      for (int fd = 0; fd < 8; ++fd) {
        int col = h * 128 + fd * 16 + fr;
        AO[(size_t)tok * 2048 + col] = f2bf(oacc[m][fd][r] * inv);
      }
    }
}

// ---------------------------------------------------------------- launcher

extern "C" void kernel_launch(void* const* d_in, const int* in_sizes, int n_in,
                              void* d_out, int out_size, void* d_ws, size_t ws_size,
                              hipStream_t stream) {
  (void)in_sizes; (void)n_in; (void)out_size; (void)ws_size;
  const int*   positions = (const int*)d_in[0];
  const float* hidden    = (const float*)d_in[1];
  const float* Wq = (const float*)d_in[2];
  const float* bq = (const float*)d_in[3];
  const float* Wk = (const float*)d_in[4];
  const float* bk = (const float*)d_in[5];
  const float* Wv = (const float*)d_in[6];
  const float* bv = (const float*)d_in[7];
  const float* Wo = (const float*)d_in[8];
  float* out = (float*)d_out;

  char* ws = (char*)d_ws;
  u16*   Xb   = (u16*)(ws);                     // 16 MB  [4096][2048]
  u16*   Wt   = (u16*)(ws + 16777216);          // 24 MB  [6144][2048]
  u16*   Wot  = (u16*)(ws + 41943040);          //  8 MB  [2048][2048]
  u16*   Qb   = (u16*)(ws + 50331648);          // 16 MB  [32][2048][128]
  u16*   Kb   = (u16*)(ws + 67108864);          // 16 MB
  u16*   Vb   = (u16*)(ws + 83886080);          // 16 MB
  u16*   Vtb  = (u16*)(ws + 100663296);         // 16 MB  [32][128][2048]
  u16*   AO   = (u16*)(ws + 117440512);         // 16 MB  [4096][2048]
  float* cosT = (float*)(ws + 134217728);       //  1 MB
  float* sinT = (float*)(ws + 135266304);       //  1 MB  (end ~130 MB)

  cvt_kernel<<<4096, 256, 0, stream>>>(hidden, Xb);
  trans_kernel<<<dim3(32, 32), 256, 0, stream>>>(Wq, Wt);
  trans_kernel<<<dim3(32, 32), 256, 0, stream>>>(Wk, Wt + (size_t)2048 * 2048);
  trans_kernel<<<dim3(32, 32), 256, 0, stream>>>(Wv, Wt + (size_t)2 * 2048 * 2048);
  trans_kernel<<<dim3(32, 32), 256, 0, stream>>>(Wo, Wot);
  rope_table_kernel<<<1024, 256, 0, stream>>>(positions, cosT, sinT);
  gemm1_kernel<<<1536, 256, 0, stream>>>(Xb, Wt, bq, bk, bv, Qb, Kb, Vb);
  rope_kernel<<<16384, 256, 0, stream>>>(Qb, Kb, cosT, sinT);
  vtrans_kernel<<<1024, 256, 0, stream>>>(Vb, Vtb);
  attn_kernel<<<256, 512, 0, stream>>>(Qb, Kb, Vtb, AO);
  gemm2_kernel<<<512, 256, 0, stream>>>(AO, Wot, out);
}